// Round 3
// baseline (535.067 us; speedup 1.0000x reference)
//
#include <hip/hip_runtime.h>

// Problem constants (from reference)
#define NCH   52            // NC
#define NSs   128           // NS (scan length)
#define NRAYS 64
#define INNER 64            // NR*NT = 4*16; one wave covers one (ray, ch) slab
#define XS    (3*NCH*INNER) // per-s stride in x       = 9984 floats
#define ZS    (2*NCH*INNER) // per-s stride in z_vals  = 6656 floats
#define NOUT  (NRAYS*NCH*INNER)  // 212992 complex outputs

// One thread per output chain: tid = ((r*NC + c)*NR + nr)*NT + nt.
// Inner 6 bits of tid are (nr,nt) -> consecutive lanes read consecutive
// addresses (256 B / wave / load, perfectly coalesced).
//
// Recurrence (reference semantics, verified):
//   f[t]   = (1-alpha[t]) * e^{-i*w*(z[t+1]-z[t])} + 1e-10   (real-part add)
//   P[s]   = prod_{t<s} f[t],  P[0] = 0  (exclusive cumprod, slot0 forced 0)
//   out    = sum_s ch[s] * (ampc/z[s]) * alpha[s] * P[s]
//
// This version: software-pipelined (loads for s+1 issued before compute of s,
// x4 unroll -> 16+ loads in flight/wave), v_rcp_f32 instead of precise div,
// oma = exp(-ar) directly, and sin/cos fed fractional REVOLUTIONS straight
// into v_sin_f32/v_cos_f32 (HW semantic: sin(2*pi*x)) — shortens the serial
// dependency chain so VMEM issue stays continuous at 13 waves/CU.
//
// Output layout: PLANAR float32 — [all 212992 reals][all 212992 imags]
__global__ __launch_bounds__(256) void render_kernel(
    const float* __restrict__ x,
    const float* __restrict__ zv,
    const float* __restrict__ fc,
    float* __restrict__ out)
{
    const int tid   = blockIdx.x * blockDim.x + threadIdx.x;   // grid is exact
    const int inner = tid & (INNER - 1);
    const int rc    = tid >> 6;
    const int c     = rc % NCH;
    const int r     = rc / NCH;

    const float* xp = x  + (size_t)r * NSs * XS + c * INNER + inner;
    const float* zp = zv + (size_t)r * NSs * ZS + c * INNER + inner;

    const double C_L    = 299792458.0;
    const double PI_D   = 3.14159265358979323846;
    const float  fcd    = fc[NCH + c];
    // revolutions per unit distance: (2*pi*fc*1e9/C)/(2*pi) = fc*1e9/C
    const double fc_rev = (double)fcd * 1.0e9 / C_L;
    const float  ampc   = (float)(C_L / ((double)fcd * 1.0e9 * 4.0 * PI_D));

    // ---- prologue, s = 0: coeffs[0] = alpha[0]*0 -> no contribution. Build f[0].
    float z_cur = zp[0];
    float z_nxt = zp[ZS];
    float ar0   = xp[(size_t)2 * NCH * INNER];
    float oma0  = __expf(-ar0);                 // (1 - alpha[0])

    double u0 = fc_rev * (double)(z_nxt - z_cur);
    u0 -= floor(u0);                            // fractional revolutions in [0,1)
    float uf0 = (float)u0;
    float sn0 = __builtin_amdgcn_sinf(uf0);     // sin(2*pi*u)
    float cs0 = __builtin_amdgcn_cosf(uf0);     // cos(2*pi*u)
    float Pre = fmaf(oma0, cs0, 1e-10f);        // f = (1-alpha)*e^{-i th} + 1e-10
    float Pim = -oma0 * sn0;                    // (+1e-10 on real part only)
    z_cur = z_nxt;                              // = z[1]

    // preload iteration s=1 operands (pipeline registers)
    float xre = xp[(size_t)1 * XS];
    float xim = xp[(size_t)1 * XS + NCH * INNER];
    float ar  = xp[(size_t)1 * XS + 2 * NCH * INNER];
    float zn  = zp[(size_t)2 * ZS];             // z[2]

    // running prefetch pointers: x(s+1), z[s+2] for loop iteration s
    const float* xq = xp + (size_t)2 * XS;      // x(2)
    const float* zq = zp + (size_t)3 * ZS;      // z[3]

    float accre = 0.0f, accim = 0.0f;

#pragma unroll 4
    for (int s = 1; s < NSs - 1; ++s) {
        // -- prefetch operands for iteration s+1 (issued before compute of s) --
        // x(s+1) is valid through s+1 = 127 (used by the epilogue).
        float n_xre = xq[0];
        float n_xim = xq[NCH * INNER];
        float n_ar  = xq[2 * NCH * INNER];
        // z[s+2] valid only while s+2 <= 127; clamp ADDRESS to z[127] at the end
        // (same value the pipeline needs there, and always in-bounds).
        const float* zsafe = (s < NSs - 2) ? zq : (zq - ZS);
        float n_zn  = zsafe[0];
        xq += XS;
        zq += ZS;

        // -- contribution for s --
        float oma   = __expf(-ar);              // (1 - alpha)
        float alpha = 1.0f - oma;
        float amp   = ampc * __builtin_amdgcn_rcpf(z_cur);   // amp_decay[s]
        float k     = alpha * amp;
        float cre   = k * Pre;
        float cim   = k * Pim;
        accre = fmaf(xre, cre, fmaf(-xim, cim, accre));
        accim = fmaf(xre, cim, fmaf( xim, cre, accim));

        // -- update P with f[s] --
        double u = fc_rev * (double)(zn - z_cur);
        u -= floor(u);                          // fractional revolutions [0,1)
        float uf = (float)u;
        float sn = __builtin_amdgcn_sinf(uf);
        float cs = __builtin_amdgcn_cosf(uf);
        float fre = fmaf(oma, cs, 1e-10f);
        float fim = -oma * sn;
        float nre = Pre * fre - Pim * fim;
        float nim = fmaf(Pre, fim, Pim * fre);
        Pre = nre;
        Pim = nim;
        z_cur = zn;

        // -- rotate pipeline registers --
        xre = n_xre; xim = n_xim; ar = n_ar; zn = n_zn;
    }

    // ---- s = NS-1: contribution only (x[127] already in pipeline regs,
    //                z_cur = z[127]; f[127] is never consumed)
    {
        float oma   = __expf(-ar);
        float alpha = 1.0f - oma;
        float amp   = ampc * __builtin_amdgcn_rcpf(z_cur);
        float k     = alpha * amp;
        accre = fmaf(xre, k * Pre, fmaf(-xim, k * Pim, accre));
        accim = fmaf(xre, k * Pim, fmaf( xim, k * Pre, accim));
    }

    // PLANAR complex output: real plane, then imag plane
    out[tid]        = accre;
    out[NOUT + tid] = accim;
}

extern "C" void kernel_launch(void* const* d_in, const int* in_sizes, int n_in,
                              void* d_out, int out_size, void* d_ws, size_t ws_size,
                              hipStream_t stream) {
    const float* x  = (const float*)d_in[0];
    const float* zv = (const float*)d_in[1];
    const float* fc = (const float*)d_in[2];
    float* out = (float*)d_out;

    render_kernel<<<NOUT / 256, 256, 0, stream>>>(x, zv, fc, out);
}